// Round 7
// baseline (60.809 us; speedup 1.0000x reference)
//
#include <hip/hip_runtime.h>

// Problem constants (fixed by setup_inputs)
constexpr int B  = 32;
constexpr int M  = 512;    // entities per batch
constexpr int N  = 128;    // channels
constexpr int H  = 128;
constexpr int W  = 128;
constexpr int HW = H * W;            // 16384 = 2^14

typedef float f4 __attribute__((ext_vector_type(4)));
typedef int   i4 __attribute__((ext_vector_type(4)));

// ---------------------------------------------------------------------------
// Single fused kernel with wave-specialized compaction.
// Grid: 32 b x 4 nh x 16 pc = 2048 blocks x 256 threads.
// Block: batch b, p-range [pc*1024, +1024), n-range [nh*32, +32).
//
// Phase 1: per-block inverse map in LDS (as before).
// Phase 1b: classify each p-quad (4 consecutive p) as valid (any entity) or
//   empty; compact quad ids so valid quads occupy slots [0, nvalid) and empty
//   quads occupy [nvalid, 256). With ~8 valid quads/block, waves 1..3 become
//   PURE dependency-free zero-store streams (the fill kernel's pattern);
//   only wave 0 carries the gather loads + vmcnt waits.
// Phase 2: slot < nvalid -> gather path (hoisted f4 loads + select + store);
//          slot >= nvalid -> 32 zero f4 stores, no loads, no waits.
// ---------------------------------------------------------------------------
__global__ __launch_bounds__(256, 4)
void fused_scatter_kernel(const float* __restrict__ x,
                          const int* __restrict__ loc,
                          float* __restrict__ out) {
    __shared__ int lmap[1024];
    __shared__ int qlist[256];
    __shared__ int cnts[2];          // [0] = #valid, [1] = #empty placed

    const int tid = threadIdx.x;
    const int bid = blockIdx.x;
    const int b  = bid >> 6;           // 64 blocks per batch
    const int nh = (bid >> 4) & 3;     // n-quarter
    const int pc = bid & 15;           // p-chunk
    const int n0 = nh << 5;            // 0,32,64,96
    const int p0 = pc << 10;

    // --- Phase 1: local inverse map ------------------------------------
    const i4 lv = *reinterpret_cast<const i4*>(loc + (b << 10) + (tid << 2));

    i4 neg = {-1, -1, -1, -1};
    *reinterpret_cast<i4*>(&lmap[tid << 2]) = neg;
    if (tid < 2) cnts[tid] = 0;
    __syncthreads();

    const int f0 = (lv[0] << 7) + lv[1] - p0;   // y*W + x - p0
    const int f1 = (lv[2] << 7) + lv[3] - p0;
    if ((unsigned)f0 < 1024u) lmap[f0] = (tid << 1);
    if ((unsigned)f1 < 1024u) lmap[f1] = (tid << 1) + 1;
    __syncthreads();

    // --- Phase 1b: compact quads (valid first, empty from the top) ------
    const i4 mv = *reinterpret_cast<const i4*>(&lmap[tid << 2]);
    const bool valid = (mv[0] >= 0) | (mv[1] >= 0) | (mv[2] >= 0) | (mv[3] >= 0);

    const int lane = tid & 63;
    const unsigned long long mask  = __ballot(valid);
    const unsigned long long below = (lane == 0) ? 0ull : (~0ull >> (64 - lane));
    const int nv_wave = __popcll(mask);

    int baseV = 0, baseI = 0;
    if (lane == 0) {
        baseV = atomicAdd(&cnts[0], nv_wave);
        baseI = atomicAdd(&cnts[1], 64 - nv_wave);
    }
    baseV = __shfl(baseV, 0);
    baseI = __shfl(baseI, 0);

    int slot;
    if (valid) slot = baseV + __popcll(mask & below);
    else       slot = 255 - (baseI + __popcll(~mask & below));
    qlist[slot] = tid;
    __syncthreads();

    const int nvalid = cnts[0];

    // --- Phase 2 ---------------------------------------------------------
    const int q  = qlist[tid];          // my quad id (0..255)
    const int pq = q << 2;              // local p base of the quad
    float* ob = out + (b << 21) + (n0 << 14) + p0 + pq;

    if (tid >= nvalid) {
        // Pure dependency-free zero-store stream: 32 channels.
        const f4 z = {0.f, 0.f, 0.f, 0.f};
        #pragma unroll
        for (int c = 0; c < 32; ++c)
            *reinterpret_cast<f4*>(ob + (c << 14)) = z;
    } else {
        const i4 iv = *reinterpret_cast<const i4*>(&lmap[pq]);
        const bool v0 = iv[0] >= 0, v1 = iv[1] >= 0, v2 = iv[2] >= 0, v3 = iv[3] >= 0;

        const float* xb = x + (b << 16) + n0;       // x[b, :, n0..], stride 128
        const float* a0 = xb + ((v0 ? iv[0] : 0) << 7);
        const float* a1 = xb + ((v1 ? iv[1] : 0) << 7);
        const float* a2 = xb + ((v2 ? iv[2] : 0) << 7);
        const float* a3 = xb + ((v3 ? iv[3] : 0) << 7);

        #pragma unroll
        for (int g = 0; g < 4; ++g) {               // 4 groups of 8 channels
            f4 xv[2][4];
            #pragma unroll
            for (int u = 0; u < 2; ++u) {           // hoisted loads: 8 f4
                const int off = (g << 3) + (u << 2);
                xv[u][0] = *reinterpret_cast<const f4*>(a0 + off);
                xv[u][1] = *reinterpret_cast<const f4*>(a1 + off);
                xv[u][2] = *reinterpret_cast<const f4*>(a2 + off);
                xv[u][3] = *reinterpret_cast<const f4*>(a3 + off);
            }
            #pragma unroll
            for (int u = 0; u < 2; ++u) {
                float* o = ob + (((g << 3) + (u << 2)) << 14);
                #pragma unroll
                for (int j = 0; j < 4; ++j) {       // n = n0 + g*8 + u*4 + j
                    f4 v = {v0 ? xv[u][0][j] : 0.f,
                            v1 ? xv[u][1][j] : 0.f,
                            v2 ? xv[u][2][j] : 0.f,
                            v3 ? xv[u][3][j] : 0.f};
                    *reinterpret_cast<f4*>(o + (j << 14)) = v;
                }
            }
        }
    }
}

// ---------------------------------------------------------------------------
extern "C" void kernel_launch(void* const* d_in, const int* in_sizes, int n_in,
                              void* d_out, int out_size, void* d_ws, size_t ws_size,
                              hipStream_t stream) {
    const float* x   = (const float*)d_in[0];
    const int*   loc = (const int*)d_in[1];
    float* out = (float*)d_out;

    fused_scatter_kernel<<<2048, 256, 0, stream>>>(x, loc, out);
}

// Round 8
// 49.144 us; speedup vs baseline: 1.2374x; 1.2374x over previous
//
#include <hip/hip_runtime.h>

// Problem constants (fixed by setup_inputs)
constexpr int B  = 32;
constexpr int M  = 512;    // entities per batch
constexpr int N  = 128;    // channels
constexpr int H  = 128;
constexpr int W  = 128;
constexpr int HW = H * W;            // 16384 = 2^14

typedef float f4 __attribute__((ext_vector_type(4)));
typedef int   i4 __attribute__((ext_vector_type(4)));

// ---------------------------------------------------------------------------
// Single fused kernel, R5 structure + explicit software pipelining.
// Grid: 32 b x 16 pc x 2 nh = 1024 blocks x 256 threads.
// Block: batch b, p-range [pc*1024, +1024), n-half [nh*64, +64).
//
// Phase 1: per-block inverse map for its p-range in LDS.
// Phase 2: thread owns p-quad (identity mapping -> perfectly coalesced
//   1 KB wave stores). 8 groups of 8 channels; loads for group g+1 are
//   issued BEFORE the stores of group g (double-buffered, static indices),
//   so store issue never serializes behind its own group's vmcnt.
// ---------------------------------------------------------------------------
__global__ __launch_bounds__(256, 4)
void fused_scatter_kernel(const float* __restrict__ x,
                          const int* __restrict__ loc,
                          float* __restrict__ out) {
    __shared__ int lmap[1024];

    const int tid = threadIdx.x;
    const int bid = blockIdx.x;
    const int b  = bid >> 5;           // 32 blocks per batch
    const int pc = (bid >> 1) & 15;    // p-chunk
    const int n0 = (bid & 1) << 6;     // n-half: 0 or 64
    const int p0 = pc << 10;

    // --- Phase 1: local inverse map ------------------------------------
    const i4 lv = *reinterpret_cast<const i4*>(loc + (b << 10) + (tid << 2));

    i4 neg = {-1, -1, -1, -1};
    *reinterpret_cast<i4*>(&lmap[tid << 2]) = neg;
    __syncthreads();

    const int f0 = (lv[0] << 7) + lv[1] - p0;   // y*W + x - p0
    const int f1 = (lv[2] << 7) + lv[3] - p0;
    if ((unsigned)f0 < 1024u) lmap[f0] = (tid << 1);
    if ((unsigned)f1 < 1024u) lmap[f1] = (tid << 1) + 1;
    __syncthreads();

    // --- Phase 2: pipelined gather + coalesced stream stores -------------
    const i4 iv = *reinterpret_cast<const i4*>(&lmap[tid << 2]);
    const bool v0 = iv[0] >= 0, v1 = iv[1] >= 0, v2 = iv[2] >= 0, v3 = iv[3] >= 0;

    const float* xb = x + (b << 16) + n0;       // x[b, :, n0..], row stride 128
    const float* a0 = xb + ((v0 ? iv[0] : 0) << 7);
    const float* a1 = xb + ((v1 ? iv[1] : 0) << 7);
    const float* a2 = xb + ((v2 ? iv[2] : 0) << 7);
    const float* a3 = xb + ((v3 ? iv[3] : 0) << 7);

    float* ob = out + (b << 21) + (n0 << 14) + p0 + (tid << 2);

    // Two register buffers, alternated with compile-time parity.
    f4 bufA[2][4], bufB[2][4];

    #define LOAD_GROUP(buf, g)                                                 \
        do {                                                                   \
            _Pragma("unroll")                                                  \
            for (int q = 0; q < 2; ++q) {                                      \
                const int off = ((g) << 3) + (q << 2);                         \
                buf[q][0] = *reinterpret_cast<const f4*>(a0 + off);            \
                buf[q][1] = *reinterpret_cast<const f4*>(a1 + off);            \
                buf[q][2] = *reinterpret_cast<const f4*>(a2 + off);            \
                buf[q][3] = *reinterpret_cast<const f4*>(a3 + off);            \
            }                                                                  \
        } while (0)

    #define STORE_GROUP(buf, g)                                                \
        do {                                                                   \
            _Pragma("unroll")                                                  \
            for (int q = 0; q < 2; ++q) {                                      \
                float* o = ob + ((((g) << 3) + (q << 2)) << 14);               \
                _Pragma("unroll")                                              \
                for (int j = 0; j < 4; ++j) {                                  \
                    f4 v = {v0 ? buf[q][0][j] : 0.f,                           \
                            v1 ? buf[q][1][j] : 0.f,                           \
                            v2 ? buf[q][2][j] : 0.f,                           \
                            v3 ? buf[q][3][j] : 0.f};                          \
                    *reinterpret_cast<f4*>(o + (j << 14)) = v;                 \
                }                                                              \
            }                                                                  \
        } while (0)

    LOAD_GROUP(bufA, 0);          // prologue
    LOAD_GROUP(bufB, 1);
    STORE_GROUP(bufA, 0);
    LOAD_GROUP(bufA, 2);
    STORE_GROUP(bufB, 1);
    LOAD_GROUP(bufB, 3);
    STORE_GROUP(bufA, 2);
    LOAD_GROUP(bufA, 4);
    STORE_GROUP(bufB, 3);
    LOAD_GROUP(bufB, 5);
    STORE_GROUP(bufA, 4);
    LOAD_GROUP(bufA, 6);
    STORE_GROUP(bufB, 5);
    LOAD_GROUP(bufB, 7);
    STORE_GROUP(bufA, 6);
    STORE_GROUP(bufB, 7);         // epilogue

    #undef LOAD_GROUP
    #undef STORE_GROUP
}

// ---------------------------------------------------------------------------
extern "C" void kernel_launch(void* const* d_in, const int* in_sizes, int n_in,
                              void* d_out, int out_size, void* d_ws, size_t ws_size,
                              hipStream_t stream) {
    const float* x   = (const float*)d_in[0];
    const int*   loc = (const int*)d_in[1];
    float* out = (float*)d_out;

    fused_scatter_kernel<<<1024, 256, 0, stream>>>(x, loc, out);
}